// Round 7
// baseline (592.228 us; speedup 1.0000x reference)
//
#include <hip/hip_runtime.h>
#include <hip/hip_bf16.h>

typedef unsigned short u16;
typedef __attribute__((ext_vector_type(8))) short short8;
typedef __attribute__((ext_vector_type(4))) float f32x4;

__device__ inline u16 f2bf(float f) {
    unsigned int u = __float_as_uint(f);
    unsigned int r = (u + 0x7fffu + ((u >> 16) & 1u)) >> 16;
    return (u16)r;
}

__device__ __forceinline__ void gload16(const u16* g, u16* l) {
    __builtin_amdgcn_global_load_lds(
        (const __attribute__((address_space(1))) void*)g,
        (__attribute__((address_space(3))) void*)l, 16, 0, 0);
}

// ---------------- weight transpose + fp32->bf16 ----------------
__global__ void transpose_cvt(const float* __restrict__ in, u16* __restrict__ out,
                              int K, int N) {
    __shared__ float tile[32][33];
    int n0 = blockIdx.x * 32, k0 = blockIdx.y * 32;
    int tx = threadIdx.x, ty = threadIdx.y;  // 32 x 8
#pragma unroll
    for (int i = 0; i < 4; i++)
        tile[ty + i * 8][tx] = in[(size_t)(k0 + ty + i * 8) * N + n0 + tx];
    __syncthreads();
#pragma unroll
    for (int i = 0; i < 4; i++)
        out[(size_t)(n0 + ty + i * 8) * K + k0 + tx] = f2bf(tile[tx][ty + i * 8]);
}

// ---------------- LayerNorm (optionally fused residual add) ----------------
template <bool ADD>
__global__ void ln_kernel(const float* __restrict__ x, const float* __restrict__ add,
                          const float* __restrict__ g, const float* __restrict__ b,
                          float* __restrict__ xa_out, u16* __restrict__ h_out) {
    int row = blockIdx.x;
    int t = threadIdx.x;
    float4 v = ((const float4*)(x + (size_t)row * 1024))[t];
    if (ADD) {
        float4 a = ((const float4*)(add + (size_t)row * 1024))[t];
        v.x += a.x; v.y += a.y; v.z += a.z; v.w += a.w;
        ((float4*)(xa_out + (size_t)row * 1024))[t] = v;
    }
    float s = v.x + v.y + v.z + v.w;
    float sq = v.x * v.x + v.y * v.y + v.z * v.z + v.w * v.w;
#pragma unroll
    for (int off = 32; off >= 1; off >>= 1) {
        s  += __shfl_xor(s, off);
        sq += __shfl_xor(sq, off);
    }
    __shared__ float ps[4], pq[4];
    int wid = t >> 6, lane = t & 63;
    if (lane == 0) { ps[wid] = s; pq[wid] = sq; }
    __syncthreads();
    s  = ps[0] + ps[1] + ps[2] + ps[3];
    sq = pq[0] + pq[1] + pq[2] + pq[3];
    float mu  = s * (1.0f / 1024.0f);
    float var = sq * (1.0f / 1024.0f) - mu * mu;
    float rstd = rsqrtf(var + 1e-5f);
    float4 gv = ((const float4*)g)[t];
    float4 bv = ((const float4*)b)[t];
    ushort4 o;
    o.x = f2bf((v.x - mu) * rstd * gv.x + bv.x);
    o.y = f2bf((v.y - mu) * rstd * gv.y + bv.y);
    o.z = f2bf((v.z - mu) * rstd * gv.z + bv.z);
    o.w = f2bf((v.w - mu) * rstd * gv.w + bv.w);
    ((ushort4*)(h_out + (size_t)row * 1024))[t] = o;
}

// ---------------- GEMM core: BM=128, BK=64, BN templated, 4 waves ----------
template <int BN>
__device__ __forceinline__ void gemm_core(
    const u16* __restrict__ A, const u16* __restrict__ Bt, int K,
    int m0, int n0, u16* As, u16* Bs, f32x4 (*acc)[BN / 32]) {
    const int NB = BN / 32;
    int t = threadIdx.x, lane = t & 63, w = t >> 6;
    int l15 = lane & 15, lhi = lane >> 4;
    int wm = (w >> 1) * 64, wn = (w & 1) * (BN / 2);

    const u16* Ag = A + (size_t)(m0 + w * 32 + (lane >> 3)) * K + (lane & 7) * 8;
    const u16* Bg = Bt + (size_t)(n0 + w * (BN / 4) + (lane >> 3)) * K + (lane & 7) * 8;
    u16* AsW = As + (w * 32) * 64;
    u16* BsW = Bs + (w * (BN / 4)) * 64;

    for (int k0 = 0; k0 < K; k0 += 64) {
        __syncthreads();
#pragma unroll
        for (int j = 0; j < 4; j++)
            gload16(Ag + k0 + (size_t)j * 8 * K, AsW + j * 8 * 64);
#pragma unroll
        for (int j = 0; j < NB; j++)
            gload16(Bg + k0 + (size_t)j * 8 * K, BsW + j * 8 * 64);
        __syncthreads();
#pragma unroll
        for (int ks = 0; ks < 2; ks++) {
            short8 af[4], bfr[NB];
#pragma unroll
            for (int mi = 0; mi < 4; mi++)
                af[mi] = *(const short8*)&As[(wm + mi * 16 + l15) * 64 + ks * 32 + lhi * 8];
#pragma unroll
            for (int ni = 0; ni < NB; ni++)
                bfr[ni] = *(const short8*)&Bs[(wn + ni * 16 + l15) * 64 + ks * 32 + lhi * 8];
#pragma unroll
            for (int mi = 0; mi < 4; mi++)
#pragma unroll
                for (int ni = 0; ni < NB; ni++)
                    acc[mi][ni] = __builtin_amdgcn_mfma_f32_16x16x32_bf16(
                        af[mi], bfr[ni], acc[mi][ni], 0, 0, 0);
        }
    }
}

// ---------------- fused QKV GEMM (blockIdx.z selects q/k/v), BN=128 -------
__global__ __launch_bounds__(256) void qkv_gemm(
    const u16* __restrict__ A,
    const u16* __restrict__ wqT, const u16* __restrict__ wkT, const u16* __restrict__ wvT,
    const float* __restrict__ bq, const float* __restrict__ bk, const float* __restrict__ bv,
    u16* __restrict__ qb, u16* __restrict__ kb, u16* __restrict__ vtb) {
    __shared__ alignas(16) u16 As[128 * 64];
    __shared__ alignas(16) u16 Bs[128 * 64];
    int z = blockIdx.z;
    const u16* Bt = z == 0 ? wqT : (z == 1 ? wkT : wvT);
    const float* bias = z == 0 ? bq : (z == 1 ? bk : bv);
    float scale = z == 0 ? 0.18033688011112042f : 1.0f;  // 0.125*log2(e)
    int n0 = blockIdx.x * 128, m0 = blockIdx.y * 128;

    f32x4 acc[4][4] = {};
    gemm_core<128>(A, Bt, 1024, m0, n0, As, Bs, acc);

    int t = threadIdx.x, lane = t & 63, w = t >> 6;
    int l15 = lane & 15, lhi = lane >> 4;
    int wm = (w >> 1) * 64, wn = (w & 1) * 64;
#pragma unroll
    for (int mi = 0; mi < 4; mi++)
#pragma unroll
        for (int ni = 0; ni < 4; ni++)
#pragma unroll
            for (int r = 0; r < 4; r++) {
                int row = m0 + wm + mi * 16 + lhi * 4 + r;
                int col = n0 + wn + ni * 16 + l15;
                u16 o = f2bf((acc[mi][ni][r] + bias[col]) * scale);
                int bb = row >> 11, ss = row & 2047, hh = col >> 6, dd = col & 63;
                if (z < 2) {
                    u16* outp = z == 0 ? qb : kb;
                    outp[(((size_t)(bb * 16 + hh) * 2048) + ss) * 64 + dd] = o;
                } else {
                    vtb[(((size_t)(bb * 16 + hh) * 64) + dd) * 2048 + ss] = o;
                }
            }
}

// ---------------- MLP GEMMs: MODE 2 = GELU->bf16, MODE 3 = +bias+resid fp32
template <int MODE, int BN>
__global__ __launch_bounds__(256) void mlp_gemm(
    const u16* __restrict__ A, const u16* __restrict__ Bt,
    const float* __restrict__ bias, void* __restrict__ outp,
    const float* __restrict__ resid, int N, int K) {
    __shared__ alignas(16) u16 As[128 * 64];
    __shared__ alignas(16) u16 Bs[BN * 64];
    int n0 = blockIdx.x * BN, m0 = blockIdx.y * 128;

    f32x4 acc[4][BN / 32] = {};
    gemm_core<BN>(A, Bt, K, m0, n0, As, Bs, acc);

    int t = threadIdx.x, lane = t & 63, w = t >> 6;
    int l15 = lane & 15, lhi = lane >> 4;
    int wm = (w >> 1) * 64, wn = (w & 1) * (BN / 2);
#pragma unroll
    for (int mi = 0; mi < 4; mi++)
#pragma unroll
        for (int ni = 0; ni < BN / 32; ni++)
#pragma unroll
            for (int r = 0; r < 4; r++) {
                int row = m0 + wm + mi * 16 + lhi * 4 + r;
                int col = n0 + wn + ni * 16 + l15;
                float val = acc[mi][ni][r] + bias[col];
                if (MODE == 2) {
                    float gl = 0.5f * val * (1.0f + erff(val * 0.70710678118654752f));
                    ((u16*)outp)[(size_t)row * N + col] = f2bf(gl);
                } else {
                    ((float*)outp)[(size_t)row * N + col] =
                        val + resid[(size_t)row * N + col];
                }
            }
}

// ---------------- fused attention, 8-wave blocks, LDS-staged K/V ----------
// q (pre-scaled by 0.125*log2e), k: [bh(32)][s(2048)][d(64)] bf16
// vt: [bh][d(64)][s(2048)] bf16
// att: [bh][s][s] fp32 ; attout: [b*s][1024] fp32
// P exchange goes through a per-wave fp32 LDS tile; an explicit
// __syncthreads() separates the cross-lane ds_write phase from the
// ds_read phase (cross-lane LDS deps are invisible to the compiler's
// per-thread alias model — without the fence it may reorder/skip waits).
__global__ __launch_bounds__(512) void attn_kernel(
    const u16* __restrict__ q, const u16* __restrict__ k,
    const u16* __restrict__ vt, float* __restrict__ att,
    float* __restrict__ attout) {
    const int S = 2048;
    int bx = blockIdx.x;
    int swz = (bx & 7) * 64 + (bx >> 3);   // 512 blocks, bijective XCD chunking
    int bh = swz >> 4;                     // 0..31
    int qb = swz & 15;                     // 0..15
    int t = threadIdx.x, w = t >> 6, lane = t & 63;
    int l15 = lane & 15, lhi = lane >> 4;
    int q0 = qb * 128 + w * 16;

    const u16* qh = q + (size_t)bh * S * 64;
    const u16* kh = k + (size_t)bh * S * 64;
    const u16* vh = vt + (size_t)bh * 64 * S;

    __shared__ alignas(16) u16 Ks[2][64][64];       // 16 KB dbuf K tiles
    __shared__ alignas(16) u16 Vs[2][64][64];       // 16 KB dbuf V tiles
    __shared__ alignas(16) float pf_all[8][16 * 36];  // 18 KB wave-private P
    float* pf = pf_all[w];

    // staging: wave w covers rows w*8..w*8+7; source col pre-swizzled
    int srow = lane >> 3;                      // 0..7
    int scol = (((lane & 7) ^ srow)) * 8;      // swizzled source octet
    const u16* kg = kh + (size_t)(w * 8 + srow) * 64 + scol;
    const u16* vg = vh + (size_t)(w * 8 + srow) * 2048 + scol;
    u16* ksl[2] = {&Ks[0][w * 8][0], &Ks[1][w * 8][0]};
    u16* vsl[2] = {&Vs[0][w * 8][0], &Vs[1][w * 8][0]};

    short8 aq0 = *(const short8*)&qh[(size_t)(q0 + l15) * 64 + lhi * 8];
    short8 aq1 = *(const short8*)&qh[(size_t)(q0 + l15) * 64 + 32 + lhi * 8];

    f32x4 z = {0.f, 0.f, 0.f, 0.f};
    float sum[4] = {0.f, 0.f, 0.f, 0.f};

    // ---- pass 1: row sums of exp2(scores) ----
    gload16(kg, ksl[0]);
    for (int i = 0; i < 32; i++) {
        __syncthreads();  // drains vmcnt: tile i ready
        if (i + 1 < 32) gload16(kg + (size_t)(i + 1) * 64 * 64, ksl[(i + 1) & 1]);
        const u16(*Kb)[64] = Ks[i & 1];
#pragma unroll
        for (int sub = 0; sub < 4; sub++) {
            int R = sub * 16 + l15;
            int cs = (R & 7) << 3;
            short8 b0 = *(const short8*)&Kb[R][(lhi * 8) ^ cs];
            short8 b1 = *(const short8*)&Kb[R][(32 + lhi * 8) ^ cs];
            f32x4 s = z;
            s = __builtin_amdgcn_mfma_f32_16x16x32_bf16(aq0, b0, s, 0, 0, 0);
            s = __builtin_amdgcn_mfma_f32_16x16x32_bf16(aq1, b1, s, 0, 0, 0);
#pragma unroll
            for (int r = 0; r < 4; r++) sum[r] += __builtin_exp2f(s[r]);
        }
    }

    float lrl[4];
#pragma unroll
    for (int r = 0; r < 4; r++) {
        float ts = sum[r];
        ts += __shfl_xor(ts, 1);
        ts += __shfl_xor(ts, 2);
        ts += __shfl_xor(ts, 4);
        ts += __shfl_xor(ts, 8);
        lrl[r] = -__log2f(ts);   // fold 1/rowsum into exp2 argument
    }

    f32x4 o[4];
#pragma unroll
    for (int ni = 0; ni < 4; ni++) o[ni] = z;

    float* attq = att + ((size_t)bh * S + q0) * S;
    int sr = lane >> 2, sc = (lane & 3) * 8;   // att-store lane mapping

    // ---- pass 2: recompute, write normalized att, accumulate P@V ----
    gload16(kg, ksl[0]);
    gload16(vg, vsl[0]);
    for (int i = 0; i < 32; i++) {
        __syncthreads();
        if (i + 1 < 32) {
            gload16(kg + (size_t)(i + 1) * 64 * 64, ksl[(i + 1) & 1]);
            gload16(vg + (i + 1) * 64, vsl[(i + 1) & 1]);
        }
        const u16(*Kb)[64] = Ks[i & 1];
        const u16(*Vb)[64] = Vs[i & 1];
#pragma unroll
        for (int kp2 = 0; kp2 < 2; kp2++) {
#pragma unroll
            for (int half = 0; half < 2; half++) {
                int R = kp2 * 32 + half * 16 + l15;
                int cs = (R & 7) << 3;
                short8 b0 = *(const short8*)&Kb[R][(lhi * 8) ^ cs];
                short8 b1 = *(const short8*)&Kb[R][(32 + lhi * 8) ^ cs];
                f32x4 s = {lrl[0], lrl[1], lrl[2], lrl[3]};
                s = __builtin_amdgcn_mfma_f32_16x16x32_bf16(aq0, b0, s, 0, 0, 0);
                s = __builtin_amdgcn_mfma_f32_16x16x32_bf16(aq1, b1, s, 0, 0, 0);
#pragma unroll
                for (int r = 0; r < 4; r++)
                    pf[(lhi * 4 + r) * 36 + half * 16 + l15] = __builtin_exp2f(s[r]);
            }
            // fence: cross-lane pf writes -> reads (compiler can't see this dep)
            __syncthreads();
            int ktb = i * 64 + kp2 * 32;
            f32x4 s0 = *(const f32x4*)&pf[sr * 36 + sc];
            f32x4 s1 = *(const f32x4*)&pf[sr * 36 + sc + 4];
            __builtin_nontemporal_store(s0, (f32x4*)&attq[(size_t)sr * S + ktb + sc]);
            __builtin_nontemporal_store(s1, (f32x4*)&attq[(size_t)sr * S + ktb + sc + 4]);
            f32x4 pa0 = *(const f32x4*)&pf[l15 * 36 + lhi * 8];
            f32x4 pa1 = *(const f32x4*)&pf[l15 * 36 + lhi * 8 + 4];
            short8 pa;
            pa[0] = (short)f2bf(pa0[0]); pa[1] = (short)f2bf(pa0[1]);
            pa[2] = (short)f2bf(pa0[2]); pa[3] = (short)f2bf(pa0[3]);
            pa[4] = (short)f2bf(pa1[0]); pa[5] = (short)f2bf(pa1[1]);
            pa[6] = (short)f2bf(pa1[2]); pa[7] = (short)f2bf(pa1[3]);
#pragma unroll
            for (int ni = 0; ni < 4; ni++) {
                int R = ni * 16 + l15;
                int cs = (R & 7) << 3;
                short8 vb = *(const short8*)&Vb[R][(kp2 * 32 + lhi * 8) ^ cs];
                o[ni] = __builtin_amdgcn_mfma_f32_16x16x32_bf16(pa, vb, o[ni], 0, 0, 0);
            }
        }
    }

    int bb = bh >> 4, hh = bh & 15;
#pragma unroll
    for (int ni = 0; ni < 4; ni++)
#pragma unroll
        for (int r = 0; r < 4; r++) {
            int srw = q0 + lhi * 4 + r;
            attout[((size_t)(bb * 2048 + srw)) * 1024 + hh * 64 + ni * 16 + l15] = o[ni][r];
        }
}

extern "C" void kernel_launch(void* const* d_in, const int* in_sizes, int n_in,
                              void* d_out, int out_size, void* d_ws, size_t ws_size,
                              hipStream_t stream) {
    const float* x    = (const float*)d_in[0];
    const float* ln_g = (const float*)d_in[1];
    const float* ln_b = (const float*)d_in[2];
    const float* wq   = (const float*)d_in[3];
    const float* bq   = (const float*)d_in[4];
    const float* wk   = (const float*)d_in[5];
    const float* bk   = (const float*)d_in[6];
    const float* wv   = (const float*)d_in[7];
    const float* bv   = (const float*)d_in[8];
    const float* w1   = (const float*)d_in[9];
    const float* b1   = (const float*)d_in[10];
    const float* w2   = (const float*)d_in[11];
    const float* b2   = (const float*)d_in[12];

    char* ws = (char*)d_ws;
    const size_t MB = 1024 * 1024;
    u16* wqT = (u16*)(ws + 0 * MB);
    u16* wkT = (u16*)(ws + 2 * MB);
    u16* wvT = (u16*)(ws + 4 * MB);
    u16* w1T = (u16*)(ws + 6 * MB);
    u16* w2T = (u16*)(ws + 14 * MB);
    u16* h1  = (u16*)(ws + 22 * MB);
    u16* qb  = (u16*)(ws + 30 * MB);
    u16* kb  = (u16*)(ws + 38 * MB);
    u16* vtb = (u16*)(ws + 46 * MB);
    u16* ub  = (u16*)(ws + 22 * MB);         // overlays h1/q/k/vt (dead then)
    float* attout = (float*)(ws + 54 * MB);
    float* xa = (float*)(ws + 70 * MB);
    u16* h2  = (u16*)(ws + 86 * MB);

    float* xout = (float*)d_out;
    float* att  = xout + (size_t)2 * 2048 * 1024;

    dim3 tb(32, 8);
    transpose_cvt<<<dim3(32, 32), tb, 0, stream>>>(wq, wqT, 1024, 1024);
    transpose_cvt<<<dim3(32, 32), tb, 0, stream>>>(wk, wkT, 1024, 1024);
    transpose_cvt<<<dim3(32, 32), tb, 0, stream>>>(wv, wvT, 1024, 1024);
    transpose_cvt<<<dim3(128, 32), tb, 0, stream>>>(w1, w1T, 1024, 4096);
    transpose_cvt<<<dim3(32, 128), tb, 0, stream>>>(w2, w2T, 4096, 1024);

    ln_kernel<false><<<4096, 256, 0, stream>>>(x, nullptr, ln_g, ln_b, nullptr, h1);

    qkv_gemm<<<dim3(8, 32, 3), 256, 0, stream>>>(h1, wqT, wkT, wvT, bq, bk, bv,
                                                 qb, kb, vtb);

    attn_kernel<<<512, 512, 0, stream>>>(qb, kb, vtb, att, attout);

    ln_kernel<true><<<4096, 256, 0, stream>>>(x, attout, ln_g, ln_b, xa, h2);

    mlp_gemm<2, 128><<<dim3(32, 32), 256, 0, stream>>>(h2, w1T, b1, ub, nullptr, 4096, 1024);
    mlp_gemm<3, 64><<<dim3(16, 32), 256, 0, stream>>>(ub, w2T, b2, xout, xa, 1024, 4096);
}

// Round 9
// 416.377 us; speedup vs baseline: 1.4223x; 1.4223x over previous
//
#include <hip/hip_runtime.h>
#include <hip/hip_bf16.h>

typedef unsigned short u16;
typedef __attribute__((ext_vector_type(8))) short short8;
typedef __attribute__((ext_vector_type(4))) float f32x4;

__device__ inline u16 f2bf(float f) {
    unsigned int u = __float_as_uint(f);
    unsigned int r = (u + 0x7fffu + ((u >> 16) & 1u)) >> 16;
    return (u16)r;
}

__device__ __forceinline__ void gload16(const u16* g, u16* l) {
    __builtin_amdgcn_global_load_lds(
        (const __attribute__((address_space(1))) void*)g,
        (__attribute__((address_space(3))) void*)l, 16, 0, 0);
}

// ---------------- weight transpose + fp32->bf16 ----------------
__global__ void transpose_cvt(const float* __restrict__ in, u16* __restrict__ out,
                              int K, int N) {
    __shared__ float tile[32][33];
    int n0 = blockIdx.x * 32, k0 = blockIdx.y * 32;
    int tx = threadIdx.x, ty = threadIdx.y;  // 32 x 8
#pragma unroll
    for (int i = 0; i < 4; i++)
        tile[ty + i * 8][tx] = in[(size_t)(k0 + ty + i * 8) * N + n0 + tx];
    __syncthreads();
#pragma unroll
    for (int i = 0; i < 4; i++)
        out[(size_t)(n0 + ty + i * 8) * K + k0 + tx] = f2bf(tile[tx][ty + i * 8]);
}

// ---------------- LayerNorm (optionally fused residual add) ----------------
template <bool ADD>
__global__ void ln_kernel(const float* __restrict__ x, const float* __restrict__ add,
                          const float* __restrict__ g, const float* __restrict__ b,
                          float* __restrict__ xa_out, u16* __restrict__ h_out) {
    int row = blockIdx.x;
    int t = threadIdx.x;
    float4 v = ((const float4*)(x + (size_t)row * 1024))[t];
    if (ADD) {
        float4 a = ((const float4*)(add + (size_t)row * 1024))[t];
        v.x += a.x; v.y += a.y; v.z += a.z; v.w += a.w;
        ((float4*)(xa_out + (size_t)row * 1024))[t] = v;
    }
    float s = v.x + v.y + v.z + v.w;
    float sq = v.x * v.x + v.y * v.y + v.z * v.z + v.w * v.w;
#pragma unroll
    for (int off = 32; off >= 1; off >>= 1) {
        s  += __shfl_xor(s, off);
        sq += __shfl_xor(sq, off);
    }
    __shared__ float ps[4], pq[4];
    int wid = t >> 6, lane = t & 63;
    if (lane == 0) { ps[wid] = s; pq[wid] = sq; }
    __syncthreads();
    s  = ps[0] + ps[1] + ps[2] + ps[3];
    sq = pq[0] + pq[1] + pq[2] + pq[3];
    float mu  = s * (1.0f / 1024.0f);
    float var = sq * (1.0f / 1024.0f) - mu * mu;
    float rstd = rsqrtf(var + 1e-5f);
    float4 gv = ((const float4*)g)[t];
    float4 bv = ((const float4*)b)[t];
    ushort4 o;
    o.x = f2bf((v.x - mu) * rstd * gv.x + bv.x);
    o.y = f2bf((v.y - mu) * rstd * gv.y + bv.y);
    o.z = f2bf((v.z - mu) * rstd * gv.z + bv.z);
    o.w = f2bf((v.w - mu) * rstd * gv.w + bv.w);
    ((ushort4*)(h_out + (size_t)row * 1024))[t] = o;
}

// ---------------- GEMM core: BM=128, BK=64, BN templated, 4 waves ----------
// T2 both-sides swizzle (rule #21): LDS dest linear (global_load_lds),
// global source octet pre-XORed by row&7, LDS read col XORed the same way.
template <int BN>
__device__ __forceinline__ void gemm_core(
    const u16* __restrict__ A, const u16* __restrict__ Bt, int K,
    int m0, int n0, u16* As, u16* Bs, f32x4 (*acc)[BN / 32]) {
    const int NB = BN / 32;
    int t = threadIdx.x, lane = t & 63, w = t >> 6;
    int l15 = lane & 15, lhi = lane >> 4;
    int wm = (w >> 1) * 64, wn = (w & 1) * (BN / 2);

    int srow8 = (lane >> 3) & 7;                    // staged row & 7
    int scol = ((lane & 7) ^ srow8) * 8;            // pre-swizzled source octet
    const u16* Ag = A + (size_t)(m0 + w * 32 + (lane >> 3)) * K + scol;
    const u16* Bg = Bt + (size_t)(n0 + w * (BN / 4) + (lane >> 3)) * K + scol;
    u16* AsW = As + (w * 32) * 64;
    u16* BsW = Bs + (w * (BN / 4)) * 64;

    int rs = (l15 & 7) << 3;                        // read-side XOR (u16 units)

    for (int k0 = 0; k0 < K; k0 += 64) {
        __syncthreads();
#pragma unroll
        for (int j = 0; j < 4; j++)
            gload16(Ag + k0 + (size_t)j * 8 * K, AsW + j * 8 * 64);
#pragma unroll
        for (int j = 0; j < NB; j++)
            gload16(Bg + k0 + (size_t)j * 8 * K, BsW + j * 8 * 64);
        __syncthreads();
#pragma unroll
        for (int ks = 0; ks < 2; ks++) {
            short8 af[4], bfr[NB];
#pragma unroll
            for (int mi = 0; mi < 4; mi++)
                af[mi] = *(const short8*)&As[(wm + mi * 16 + l15) * 64 +
                                             ((ks * 32 + lhi * 8) ^ rs)];
#pragma unroll
            for (int ni = 0; ni < NB; ni++)
                bfr[ni] = *(const short8*)&Bs[(wn + ni * 16 + l15) * 64 +
                                              ((ks * 32 + lhi * 8) ^ rs)];
#pragma unroll
            for (int mi = 0; mi < 4; mi++)
#pragma unroll
                for (int ni = 0; ni < NB; ni++)
                    acc[mi][ni] = __builtin_amdgcn_mfma_f32_16x16x32_bf16(
                        af[mi], bfr[ni], acc[mi][ni], 0, 0, 0);
        }
    }
}

// ---------------- fused QKV GEMM (blockIdx.z selects q/k/v), BN=128 -------
__global__ __launch_bounds__(256) void qkv_gemm(
    const u16* __restrict__ A,
    const u16* __restrict__ wqT, const u16* __restrict__ wkT, const u16* __restrict__ wvT,
    const float* __restrict__ bq, const float* __restrict__ bk, const float* __restrict__ bv,
    u16* __restrict__ qb, u16* __restrict__ kb, u16* __restrict__ vtb) {
    __shared__ alignas(16) u16 As[128 * 64];
    __shared__ alignas(16) u16 Bs[128 * 64];
    int z = blockIdx.z;
    const u16* Bt = z == 0 ? wqT : (z == 1 ? wkT : wvT);
    const float* bias = z == 0 ? bq : (z == 1 ? bk : bv);
    float scale = z == 0 ? 0.18033688011112042f : 1.0f;  // 0.125*log2(e)
    int n0 = blockIdx.x * 128, m0 = blockIdx.y * 128;

    f32x4 acc[4][4] = {};
    gemm_core<128>(A, Bt, 1024, m0, n0, As, Bs, acc);

    int t = threadIdx.x, lane = t & 63, w = t >> 6;
    int l15 = lane & 15, lhi = lane >> 4;
    int wm = (w >> 1) * 64, wn = (w & 1) * 64;
#pragma unroll
    for (int mi = 0; mi < 4; mi++)
#pragma unroll
        for (int ni = 0; ni < 4; ni++)
#pragma unroll
            for (int r = 0; r < 4; r++) {
                int row = m0 + wm + mi * 16 + lhi * 4 + r;
                int col = n0 + wn + ni * 16 + l15;
                u16 o = f2bf((acc[mi][ni][r] + bias[col]) * scale);
                int bb = row >> 11, ss = row & 2047, hh = col >> 6, dd = col & 63;
                if (z < 2) {
                    u16* outp = z == 0 ? qb : kb;
                    outp[(((size_t)(bb * 16 + hh) * 2048) + ss) * 64 + dd] = o;
                } else {
                    vtb[(((size_t)(bb * 16 + hh) * 64) + dd) * 2048 + ss] = o;
                }
            }
}

// ---------------- MLP GEMMs: MODE 2 = GELU->bf16, MODE 3 = +bias+resid fp32
template <int MODE, int BN>
__global__ __launch_bounds__(256) void mlp_gemm(
    const u16* __restrict__ A, const u16* __restrict__ Bt,
    const float* __restrict__ bias, void* __restrict__ outp,
    const float* __restrict__ resid, int N, int K) {
    __shared__ alignas(16) u16 As[128 * 64];
    __shared__ alignas(16) u16 Bs[BN * 64];
    int n0 = blockIdx.x * BN, m0 = blockIdx.y * 128;

    f32x4 acc[4][BN / 32] = {};
    gemm_core<BN>(A, Bt, K, m0, n0, As, Bs, acc);

    int t = threadIdx.x, lane = t & 63, w = t >> 6;
    int l15 = lane & 15, lhi = lane >> 4;
    int wm = (w >> 1) * 64, wn = (w & 1) * (BN / 2);
#pragma unroll
    for (int mi = 0; mi < 4; mi++)
#pragma unroll
        for (int ni = 0; ni < BN / 32; ni++)
#pragma unroll
            for (int r = 0; r < 4; r++) {
                int row = m0 + wm + mi * 16 + lhi * 4 + r;
                int col = n0 + wn + ni * 16 + l15;
                float val = acc[mi][ni][r] + bias[col];
                if (MODE == 2) {
                    float gl = 0.5f * val * (1.0f + erff(val * 0.70710678118654752f));
                    ((u16*)outp)[(size_t)row * N + col] = f2bf(gl);
                } else {
                    ((float*)outp)[(size_t)row * N + col] =
                        val + resid[(size_t)row * N + col];
                }
            }
}

// ---------------- fused attention, 8-wave blocks, LDS-staged K/V ----------
// q (pre-scaled by 0.125*log2e), k: [bh(32)][s(2048)][d(64)] bf16
// vt: [bh][d(64)][s(2048)] bf16
// att: [bh][s][s] fp32 ; attout: [b*s][1024] fp32
// pf exchange fence: sched_barrier + wave lgkmcnt + RAW s_barrier +
// sched_barrier. Raw s_barrier does NOT drain vmcnt (K/V prefetch stays in
// flight, unlike __syncthreads) but is a hard compiler reorder point.
// Round-8 lesson (rule #18 class): one-sided fence leaked -> nondeterminism.
__global__ __launch_bounds__(512) void attn_kernel(
    const u16* __restrict__ q, const u16* __restrict__ k,
    const u16* __restrict__ vt, float* __restrict__ att,
    float* __restrict__ attout) {
    const int S = 2048;
    int bx = blockIdx.x;
    int swz = (bx & 7) * 64 + (bx >> 3);   // 512 blocks, bijective XCD chunking
    int bh = swz >> 4;                     // 0..31
    int qb = swz & 15;                     // 0..15
    int t = threadIdx.x, w = t >> 6, lane = t & 63;
    int l15 = lane & 15, lhi = lane >> 4;
    int q0 = qb * 128 + w * 16;

    const u16* qh = q + (size_t)bh * S * 64;
    const u16* kh = k + (size_t)bh * S * 64;
    const u16* vh = vt + (size_t)bh * 64 * S;

    __shared__ alignas(16) u16 Ks[2][64][64];       // 16 KB dbuf K tiles
    __shared__ alignas(16) u16 Vs[2][64][64];       // 16 KB dbuf V tiles
    __shared__ alignas(16) float pf_all[8][16 * 36];  // 18 KB wave-private P
    float* pf = pf_all[w];

    // staging: wave w covers rows w*8..w*8+7; source col pre-swizzled
    int srow = lane >> 3;                      // 0..7
    int scol = (((lane & 7) ^ srow)) * 8;      // swizzled source octet
    const u16* kg = kh + (size_t)(w * 8 + srow) * 64 + scol;
    const u16* vg = vh + (size_t)(w * 8 + srow) * 2048 + scol;
    u16* ksl[2] = {&Ks[0][w * 8][0], &Ks[1][w * 8][0]};
    u16* vsl[2] = {&Vs[0][w * 8][0], &Vs[1][w * 8][0]};

    short8 aq0 = *(const short8*)&qh[(size_t)(q0 + l15) * 64 + lhi * 8];
    short8 aq1 = *(const short8*)&qh[(size_t)(q0 + l15) * 64 + 32 + lhi * 8];

    f32x4 z = {0.f, 0.f, 0.f, 0.f};
    float sum[4] = {0.f, 0.f, 0.f, 0.f};

    // ---- pass 1: row sums of exp2(scores) ----
    gload16(kg, ksl[0]);
    for (int i = 0; i < 32; i++) {
        __syncthreads();  // drains vmcnt: tile i ready
        if (i + 1 < 32) gload16(kg + (size_t)(i + 1) * 64 * 64, ksl[(i + 1) & 1]);
        const u16(*Kb)[64] = Ks[i & 1];
#pragma unroll
        for (int sub = 0; sub < 4; sub++) {
            int R = sub * 16 + l15;
            int cs = (R & 7) << 3;
            short8 b0 = *(const short8*)&Kb[R][(lhi * 8) ^ cs];
            short8 b1 = *(const short8*)&Kb[R][(32 + lhi * 8) ^ cs];
            f32x4 s = z;
            s = __builtin_amdgcn_mfma_f32_16x16x32_bf16(aq0, b0, s, 0, 0, 0);
            s = __builtin_amdgcn_mfma_f32_16x16x32_bf16(aq1, b1, s, 0, 0, 0);
#pragma unroll
            for (int r = 0; r < 4; r++) sum[r] += __builtin_exp2f(s[r]);
        }
    }

    float lrl[4];
#pragma unroll
    for (int r = 0; r < 4; r++) {
        float ts = sum[r];
        ts += __shfl_xor(ts, 1);
        ts += __shfl_xor(ts, 2);
        ts += __shfl_xor(ts, 4);
        ts += __shfl_xor(ts, 8);
        lrl[r] = -__log2f(ts);   // fold 1/rowsum into exp2 argument
    }

    f32x4 o[4];
#pragma unroll
    for (int ni = 0; ni < 4; ni++) o[ni] = z;

    float* attq = att + ((size_t)bh * S + q0) * S;
    int sr = lane >> 2, sc = (lane & 3) * 8;   // att-store lane mapping

    // ---- pass 2: recompute, write normalized att, accumulate P@V ----
    gload16(kg, ksl[0]);
    gload16(vg, vsl[0]);
    for (int i = 0; i < 32; i++) {
        __syncthreads();
        if (i + 1 < 32) {
            gload16(kg + (size_t)(i + 1) * 64 * 64, ksl[(i + 1) & 1]);
            gload16(vg + (i + 1) * 64, vsl[(i + 1) & 1]);
        }
        const u16(*Kb)[64] = Ks[i & 1];
        const u16(*Vb)[64] = Vs[i & 1];
#pragma unroll
        for (int kp2 = 0; kp2 < 2; kp2++) {
#pragma unroll
            for (int half = 0; half < 2; half++) {
                int R = kp2 * 32 + half * 16 + l15;
                int cs = (R & 7) << 3;
                short8 b0 = *(const short8*)&Kb[R][(lhi * 8) ^ cs];
                short8 b1 = *(const short8*)&Kb[R][(32 + lhi * 8) ^ cs];
                f32x4 s = {lrl[0], lrl[1], lrl[2], lrl[3]};
                s = __builtin_amdgcn_mfma_f32_16x16x32_bf16(aq0, b0, s, 0, 0, 0);
                s = __builtin_amdgcn_mfma_f32_16x16x32_bf16(aq1, b1, s, 0, 0, 0);
#pragma unroll
                for (int r = 0; r < 4; r++)
                    pf[(lhi * 4 + r) * 36 + half * 16 + l15] = __builtin_exp2f(s[r]);
            }
            // two-sided fence around the wave-local lgkmcnt wait + raw
            // s_barrier (no vmcnt drain; prefetch stays in flight).
            __builtin_amdgcn_sched_barrier(0);
            asm volatile("s_waitcnt lgkmcnt(0)" ::: "memory");
            __builtin_amdgcn_s_barrier();
            __builtin_amdgcn_sched_barrier(0);
            int ktb = i * 64 + kp2 * 32;
            f32x4 s0 = *(const f32x4*)&pf[sr * 36 + sc];
            f32x4 s1 = *(const f32x4*)&pf[sr * 36 + sc + 4];
            *(f32x4*)&attq[(size_t)sr * S + ktb + sc] = s0;
            *(f32x4*)&attq[(size_t)sr * S + ktb + sc + 4] = s1;
            f32x4 pa0 = *(const f32x4*)&pf[l15 * 36 + lhi * 8];
            f32x4 pa1 = *(const f32x4*)&pf[l15 * 36 + lhi * 8 + 4];
            short8 pa;
            pa[0] = (short)f2bf(pa0[0]); pa[1] = (short)f2bf(pa0[1]);
            pa[2] = (short)f2bf(pa0[2]); pa[3] = (short)f2bf(pa0[3]);
            pa[4] = (short)f2bf(pa1[0]); pa[5] = (short)f2bf(pa1[1]);
            pa[6] = (short)f2bf(pa1[2]); pa[7] = (short)f2bf(pa1[3]);
#pragma unroll
            for (int ni = 0; ni < 4; ni++) {
                int R = ni * 16 + l15;
                int cs = (R & 7) << 3;
                short8 vb = *(const short8*)&Vb[R][(kp2 * 32 + lhi * 8) ^ cs];
                o[ni] = __builtin_amdgcn_mfma_f32_16x16x32_bf16(pa, vb, o[ni], 0, 0, 0);
            }
        }
    }

    int bb = bh >> 4, hh = bh & 15;
#pragma unroll
    for (int ni = 0; ni < 4; ni++)
#pragma unroll
        for (int r = 0; r < 4; r++) {
            int srw = q0 + lhi * 4 + r;
            attout[((size_t)(bb * 2048 + srw)) * 1024 + hh * 64 + ni * 16 + l15] = o[ni][r];
        }
}

extern "C" void kernel_launch(void* const* d_in, const int* in_sizes, int n_in,
                              void* d_out, int out_size, void* d_ws, size_t ws_size,
                              hipStream_t stream) {
    const float* x    = (const float*)d_in[0];
    const float* ln_g = (const float*)d_in[1];
    const float* ln_b = (const float*)d_in[2];
    const float* wq   = (const float*)d_in[3];
    const float* bq   = (const float*)d_in[4];
    const float* wk   = (const float*)d_in[5];
    const float* bk   = (const float*)d_in[6];
    const float* wv   = (const float*)d_in[7];
    const float* bv   = (const float*)d_in[8];
    const float* w1   = (const float*)d_in[9];
    const float* b1   = (const float*)d_in[10];
    const float* w2   = (const float*)d_in[11];
    const float* b2   = (const float*)d_in[12];

    char* ws = (char*)d_ws;
    const size_t MB = 1024 * 1024;
    u16* wqT = (u16*)(ws + 0 * MB);
    u16* wkT = (u16*)(ws + 2 * MB);
    u16* wvT = (u16*)(ws + 4 * MB);
    u16* w1T = (u16*)(ws + 6 * MB);
    u16* w2T = (u16*)(ws + 14 * MB);
    u16* h1  = (u16*)(ws + 22 * MB);
    u16* qb  = (u16*)(ws + 30 * MB);
    u16* kb  = (u16*)(ws + 38 * MB);
    u16* vtb = (u16*)(ws + 46 * MB);
    u16* ub  = (u16*)(ws + 22 * MB);         // overlays h1/q/k/vt (dead then)
    float* attout = (float*)(ws + 54 * MB);
    float* xa = (float*)(ws + 70 * MB);
    u16* h2  = (u16*)(ws + 86 * MB);

    float* xout = (float*)d_out;
    float* att  = xout + (size_t)2 * 2048 * 1024;

    dim3 tb(32, 8);
    transpose_cvt<<<dim3(32, 32), tb, 0, stream>>>(wq, wqT, 1024, 1024);
    transpose_cvt<<<dim3(32, 32), tb, 0, stream>>>(wk, wkT, 1024, 1024);
    transpose_cvt<<<dim3(32, 32), tb, 0, stream>>>(wv, wvT, 1024, 1024);
    transpose_cvt<<<dim3(128, 32), tb, 0, stream>>>(w1, w1T, 1024, 4096);
    transpose_cvt<<<dim3(32, 128), tb, 0, stream>>>(w2, w2T, 4096, 1024);

    ln_kernel<false><<<4096, 256, 0, stream>>>(x, nullptr, ln_g, ln_b, nullptr, h1);

    qkv_gemm<<<dim3(8, 32, 3), 256, 0, stream>>>(h1, wqT, wkT, wvT, bq, bk, bv,
                                                 qb, kb, vtb);

    attn_kernel<<<512, 512, 0, stream>>>(qb, kb, vtb, att, attout);

    ln_kernel<true><<<4096, 256, 0, stream>>>(x, attout, ln_g, ln_b, xa, h2);

    mlp_gemm<2, 128><<<dim3(32, 32), 256, 0, stream>>>(h2, w1T, b1, ub, nullptr, 4096, 1024);
    mlp_gemm<3, 64><<<dim3(16, 32), 256, 0, stream>>>(ub, w2T, b2, xout, xa, 1024, 4096);
}